// Round 13
// baseline (403.328 us; speedup 1.0000x reference)
//
#include <hip/hip_runtime.h>
#include <hip/hip_fp16.h>

// Affinity propagation: 24 Jacobi iterations of an 8-neighbor weighted stencil.
// OFFSETS (dy,dx): (-1,-1),(-1,0),(-1,1),(0,-1),(0,1),(1,-1),(1,0),(1,1)
// R13: ONE propagation launch. Tile 64x144, core 40x120 (flush: 16x4x8 = 512
// blocks), 36 px/thread (4x9). Weights (144 VGPR) + bias stay in registers
// across ALL 24 iterations; mid-way device-wide barrier (atomic arrive+spin,
// residency checked host-side via occupancy query; falls back to 2 launches
// if <2 blocks/CU). Weight traffic 201MB -> 76MB vs R12.
// LESSONS: __launch_bounds__(256,4) clamps VGPR->64 = spill disaster (R8).
// Keep store predicates cheap/static-ish (R9/R10). Spill signature = huge
// FETCH_SIZE + VGPR cap in counters.

#define EPSV 1e-6f
#define RING   12
#define CORE_W 40
#define CORE_H 120
#define TILE_W 64
#define TILE_H 144
#define TXN    16                  // 640/40
#define TYN    4                   // 480/120
#define NBLK   (8 * TXN * TYN)     // 512
#define SEGS   16
#define RPS    9                   // rows per thread (TILE_H / SEGS)

typedef __attribute__((ext_vector_type(8))) _Float16 half8;
typedef __attribute__((ext_vector_type(4))) _Float16 half4;

__device__ __forceinline__ float dpp_from_left(float v) {
    // lane i gets lane i-1's v (within 16-lane DPP row); qx==0 -> 0.
    int r = __builtin_amdgcn_update_dpp(0, __float_as_int(v), 0x111, 0xF, 0xF, true);
    return __int_as_float(r);
}
__device__ __forceinline__ float dpp_from_right(float v) {
    // lane i gets lane i+1's v; qx==15 -> 0.
    int r = __builtin_amdgcn_update_dpp(0, __float_as_int(v), 0x101, 0xF, 0xF, true);
    return __int_as_float(r);
}

// ---------------------------------------------------------------------------
// Kernel 1: normalize guidance -> fp16 weights (AoS), fp16 bias, fp16 state.
// ---------------------------------------------------------------------------
__global__ __launch_bounds__(256) void precompute_kernel(
    const float* __restrict__ guidance, const float* __restrict__ raw,
    half8* __restrict__ wgt, _Float16* __restrict__ bias,
    _Float16* __restrict__ state, int B, int H, int W)
{
    int idx = blockIdx.x * blockDim.x + threadIdx.x;
    int total = B * H * W;
    if (idx >= total) return;
    int x = idx % W;
    int y = (idx / W) % H;
    int b = idx / (W * H);

    const int dy[8] = {-1,-1,-1, 0, 0, 1, 1, 1};
    const int dx[8] = {-1, 0, 1,-1, 1,-1, 0, 1};

    float g[8];
    float s = 0.f;
#pragma unroll
    for (int c = 0; c < 8; ++c) {
        int yy = y + dy[c], xx = x + dx[c];
        float v = 0.f;
        if (yy >= 0 && yy < H && xx >= 0 && xx < W)
            v = guidance[(((size_t)b * 8 + c) * H + yy) * W + xx];
        g[c] = v;
        s += fabsf(v);
    }
    float inv = 1.f / fmaxf(s, EPSV);
    float wsum = 0.f;
#pragma unroll
    for (int c = 0; c < 8; ++c) { g[c] *= inv; wsum += g[c]; }

    half8 hw;
#pragma unroll
    for (int c = 0; c < 8; ++c) hw[c] = (_Float16)g[c];
    wgt[idx] = hw;

    float r = raw[idx];
    bias[idx]  = (_Float16)((1.f - wsum) * r);
    state[idx] = (_Float16)r;
}

// ---------------------------------------------------------------------------
// Device-wide barrier: all NBLK blocks resident (verified host-side).
// ---------------------------------------------------------------------------
__device__ __forceinline__ void grid_sync(unsigned* cnt) {
    __syncthreads();
    if (threadIdx.x == 0) {
        __threadfence();                       // release my global writes
        atomicAdd(cnt, 1u);                    // device-scope by default
        while (__hip_atomic_load(cnt, __ATOMIC_RELAXED,
                                 __HIP_MEMORY_SCOPE_AGENT) < NBLK)
            __builtin_amdgcn_s_sleep(32);
    }
    __syncthreads();
    __threadfence();                           // acquire: fresh reads below
}

// ---------------------------------------------------------------------------
// 12 Jacobi iterations on register state (RPS rows x 4 px per thread).
// DPP horizontal exchange; LDS for segment-boundary rows; ping-pong parity.
// ---------------------------------------------------------------------------
__device__ __forceinline__ void run_half(
    float (&sv)[RPS][4], const half8 (&pw)[RPS][4], const half4 (&pbq)[RPS],
    int qx, int seg,
    float (*bufTop)[SEGS + 1][TILE_W], float (*bufBot)[SEGS + 1][TILE_W])
{
#pragma unroll 2
    for (int it = 0; it < RING; ++it) {
        const int p = it & 1;
        *(float4*)&bufTop[p][seg][qx * 4] =
            make_float4(sv[0][0], sv[0][1], sv[0][2], sv[0][3]);
        *(float4*)&bufBot[p][seg + 1][qx * 4] =
            make_float4(sv[RPS-1][0], sv[RPS-1][1], sv[RPS-1][2], sv[RPS-1][3]);
        __syncthreads();
        float4 Av = *(const float4*)&bufBot[p][seg][qx * 4];      // above row
        float4 Bv = *(const float4*)&bufTop[p][seg + 1][qx * 4];  // below row

        float u0 = Av.x, u1 = Av.y, u2 = Av.z, u3 = Av.w;
        float ul = dpp_from_left(u3);
        float ur = dpp_from_right(u0);
        float cl = dpp_from_left(sv[0][3]);
        float cr = dpp_from_right(sv[0][0]);
#pragma unroll
        for (int r = 0; r < RPS; ++r) {
            float D0, D1, D2, D3;
            if (r < RPS - 1) { D0 = sv[r+1][0]; D1 = sv[r+1][1];
                               D2 = sv[r+1][2]; D3 = sv[r+1][3]; }
            else             { D0 = Bv.x; D1 = Bv.y; D2 = Bv.z; D3 = Bv.w; }
            float dl = dpp_from_left(D3);
            float dr = dpp_from_right(D0);
            float C0 = sv[r][0], C1 = sv[r][1], C2 = sv[r][2], C3 = sv[r][3];
            half8 w0 = pw[r][0], w1 = pw[r][1], w2 = pw[r][2], w3 = pw[r][3];
            float n0 = (float)pbq[r][0]
                + (float)w0[0] * ul + (float)w0[1] * u0 + (float)w0[2] * u1
                + (float)w0[3] * cl + (float)w0[4] * C1
                + (float)w0[5] * dl + (float)w0[6] * D0 + (float)w0[7] * D1;
            float n1 = (float)pbq[r][1]
                + (float)w1[0] * u0 + (float)w1[1] * u1 + (float)w1[2] * u2
                + (float)w1[3] * C0 + (float)w1[4] * C2
                + (float)w1[5] * D0 + (float)w1[6] * D1 + (float)w1[7] * D2;
            float n2 = (float)pbq[r][2]
                + (float)w2[0] * u1 + (float)w2[1] * u2 + (float)w2[2] * u3
                + (float)w2[3] * C1 + (float)w2[4] * C3
                + (float)w2[5] * D1 + (float)w2[6] * D2 + (float)w2[7] * D3;
            float n3 = (float)pbq[r][3]
                + (float)w3[0] * u2 + (float)w3[1] * u3 + (float)w3[2] * ur
                + (float)w3[3] * C2 + (float)w3[4] * cr
                + (float)w3[5] * D2 + (float)w3[6] * D3 + (float)w3[7] * dr;
            u0 = C0; u1 = C1; u2 = C2; u3 = C3; ul = cl; ur = cr;
            cl = dl; cr = dr;
            sv[r][0] = n0; sv[r][1] = n1; sv[r][2] = n2; sv[r][3] = n3;
        }
    }
}

// ---------------------------------------------------------------------------
// MODE 0: half1 (src -> mid fp16). MODE 1: half2 (mid -> out f32).
// MODE 2: both halves in one launch, grid barrier between (weights stay in
// registers). Recompute-ring correctness: outside-tile treated as 0 each
// iter; after 12 iters px at L-inf distance >= 13 from tile exterior (the
// 40x120 core) are exact. Out-of-image px have w=0,b=0,s=0 -> stay 0
// (zero-pad exact). Cores tile the image disjointly and flush.
// ---------------------------------------------------------------------------
template<int MODE>
__global__ __launch_bounds__(256) void prop_fused_kernel(
    const _Float16* __restrict__ src, const half8* __restrict__ wgt,
    const _Float16* __restrict__ bias, _Float16* __restrict__ mid,
    float* __restrict__ out, unsigned* cnt)
{
    const int H = 480, W = 640;
    __shared__ __align__(16) float bufTop[2][SEGS + 1][TILE_W];
    __shared__ __align__(16) float bufBot[2][SEGS + 1][TILE_W];

    int tid = threadIdx.x;
    int qx  = tid & 15;
    int seg = tid >> 4;

    int t = blockIdx.x;
    int tx = t % TXN;
    int tmp = t / TXN;
    int ty = tmp % TYN;
    int b  = tmp / TYN;
    int x0 = tx * CORE_W - RING;
    int y0 = ty * CORE_H - RING;
    size_t plane = (size_t)b * H * W;

    int gx0 = x0 + qx * 4;                    // quad fully in or out of image
    bool xok = (gx0 >= 0) & (gx0 + 3 < W);
    int gyb = y0 + seg * RPS;

    if (tid < TILE_W) {
        bufBot[0][0][tid] = 0.f;    bufBot[1][0][tid] = 0.f;
        bufTop[0][SEGS][tid] = 0.f; bufTop[1][SEGS][tid] = 0.f;
    }

    half8 pw[RPS][4];
    half4 pbq[RPS];
    float sv[RPS][4];

    const _Float16* st0 = (MODE == 1) ? mid : src;

#pragma unroll
    for (int r = 0; r < RPS; ++r) {
        int gy = gyb + r;
        bool ok = xok && gy >= 0 && gy < H;
        if (ok) {
            size_t gb = plane + (size_t)gy * W + gx0;
            const half8* wp = wgt + gb;
            pw[r][0] = wp[0]; pw[r][1] = wp[1]; pw[r][2] = wp[2]; pw[r][3] = wp[3];
            pbq[r] = *(const half4*)(bias + gb);
            half4 sq = *(const half4*)(st0 + gb);
#pragma unroll
            for (int c = 0; c < 4; ++c) sv[r][c] = (float)sq[c];
        } else {
            half8 hz;
#pragma unroll
            for (int c = 0; c < 8; ++c) hz[c] = (_Float16)0.f;
            half4 z4;
#pragma unroll
            for (int c = 0; c < 4; ++c) z4[c] = (_Float16)0.f;
            pbq[r] = z4;
#pragma unroll
            for (int c = 0; c < 4; ++c) { pw[r][c] = hz; sv[r][c] = 0.f; }
        }
    }

    run_half(sv, pw, pbq, qx, seg, bufTop, bufBot);

    bool corex = (qx >= 3) & (qx < 13);

    if (MODE == 0 || MODE == 2) {
        // Write core state fp16 to mid.
        if (corex) {
#pragma unroll
            for (int r = 0; r < RPS; ++r) {
                int trow = seg * RPS + r;
                if (trow >= RING && trow < RING + CORE_H) {
                    size_t gb = plane + (size_t)(gyb + r) * W + gx0;
                    half4 hv;
                    hv[0] = (_Float16)sv[r][0]; hv[1] = (_Float16)sv[r][1];
                    hv[2] = (_Float16)sv[r][2]; hv[3] = (_Float16)sv[r][3];
                    *(half4*)(mid + gb) = hv;
                }
            }
        }
    }
    if (MODE == 0) return;

    if (MODE == 2) {
        grid_sync(cnt);
        // Re-stage state only (weights/bias still in registers).
#pragma unroll
        for (int r = 0; r < RPS; ++r) {
            int gy = gyb + r;
            bool ok = xok && gy >= 0 && gy < H;
            if (ok) {
                size_t gb = plane + (size_t)gy * W + gx0;
                half4 sq = *(const half4*)(mid + gb);
#pragma unroll
                for (int c = 0; c < 4; ++c) sv[r][c] = (float)sq[c];
            } else {
#pragma unroll
                for (int c = 0; c < 4; ++c) sv[r][c] = 0.f;
            }
        }
        run_half(sv, pw, pbq, qx, seg, bufTop, bufBot);
    }
    if (MODE == 1) {
        // (fresh launch already staged from mid and ran 12 iters above)
    }

    // Final store f32.
    if (corex) {
#pragma unroll
        for (int r = 0; r < RPS; ++r) {
            int trow = seg * RPS + r;
            if (trow >= RING && trow < RING + CORE_H) {
                size_t gb = plane + (size_t)(gyb + r) * W + gx0;
                *(float4*)(out + gb) =
                    make_float4(sv[r][0], sv[r][1], sv[r][2], sv[r][3]);
            }
        }
    }
}

// ---------------------------------------------------------------------------
extern "C" void kernel_launch(void* const* d_in, const int* in_sizes, int n_in,
                              void* d_out, int out_size, void* d_ws, size_t ws_size,
                              hipStream_t stream) {
    const float* guidance = (const float*)d_in[0];
    const float* raw      = (const float*)d_in[1];
    float* out = (float*)d_out;

    const int B = 8, H = 480, W = 640;
    const size_t npix = (size_t)B * H * W;

    // Workspace: wgt half8 (npix*16B) | bias fp16 | p0 fp16 | p1 fp16 | cnt
    half8*    wgt  = (half8*)d_ws;
    _Float16* bias = (_Float16*)((char*)d_ws + npix * sizeof(half8));
    _Float16* p0   = bias + npix;
    _Float16* p1   = p0 + npix;
    unsigned* cnt  = (unsigned*)((char*)(p1 + npix));

    {
        int blocks = (int)((npix + 255) / 256);
        precompute_kernel<<<blocks, 256, 0, stream>>>(guidance, raw, wgt, bias,
                                                      p0, B, H, W);
    }

    // Residency check: grid barrier needs all 512 blocks co-resident.
    int maxb = 0;
    (void)hipOccupancyMaxActiveBlocksPerMultiprocessor(
        &maxb, prop_fused_kernel<2>, 256, 0);

    if (maxb >= 2) {
        (void)hipMemsetAsync(cnt, 0, sizeof(unsigned), stream);
        prop_fused_kernel<2><<<NBLK, 256, 0, stream>>>(p0, wgt, bias, p1, out, cnt);
    } else {
        // Fallback: two launches, weights re-staged (no cross-block spin).
        prop_fused_kernel<0><<<NBLK, 256, 0, stream>>>(p0, wgt, bias, p1, out, cnt);
        prop_fused_kernel<1><<<NBLK, 256, 0, stream>>>(p0, wgt, bias, p1, out, cnt);
    }
}

// Round 14
// 103.926 us; speedup vs baseline: 3.8809x; 3.8809x over previous
//
#include <hip/hip_runtime.h>
#include <hip/hip_fp16.h>

// Affinity propagation: 24 Jacobi iterations of an 8-neighbor weighted stencil.
// OFFSETS (dy,dx): (-1,-1),(-1,0),(-1,1),(0,-1),(0,1),(1,-1),(1,0),(1,1)
// R14 = R12 (FUSE=12, 64x64 tile, 40x40 flush core, register weights, DPP
// horizontal + LDS vertical exchange) with PERSISTENT 2-TILE BLOCKS:
// NBLK=768, each block runs tile bid then bid+768 sequentially. 768 blocks
// <= resident capacity -> one balanced phase (R12's 1536 ran as 1024 + 512
// half-empty phase). Tile-2 staging overlaps other blocks' compute.
// LESSONS: __launch_bounds__(256,4) clamps VGPR->64 = spill (R8). RPS=9
// state = 256 VGPR + spill (R13). Runtime store bounds regress (R9/R10).
// Spill signature in counters: VGPR at cap + FETCH_SIZE >> logical.

#define EPSV 1e-6f
#define FUSE   12
#define CORE   40                 // output core per 64x64 tile
#define TXN    16                 // 640 / 40
#define TYN    12                 // 480 / 40
#define NTILE_TOT (8 * TXN * TYN) // 1536
#define NBLK   (NTILE_TOT / 2)    // 768

typedef __attribute__((ext_vector_type(8))) _Float16 half8;
typedef __attribute__((ext_vector_type(4))) _Float16 half4;

__device__ __forceinline__ float dpp_from_left(float v) {
    // lane i gets lane i-1's v (within 16-lane DPP row); qx==0 -> 0.
    int r = __builtin_amdgcn_update_dpp(0, __float_as_int(v), 0x111, 0xF, 0xF, true);
    return __int_as_float(r);
}
__device__ __forceinline__ float dpp_from_right(float v) {
    // lane i gets lane i+1's v; qx==15 -> 0.
    int r = __builtin_amdgcn_update_dpp(0, __float_as_int(v), 0x101, 0xF, 0xF, true);
    return __int_as_float(r);
}

// ---------------------------------------------------------------------------
// Kernel 1: normalize guidance -> fp16 weights (AoS), fp16 bias, fp16 state.
// ---------------------------------------------------------------------------
__global__ __launch_bounds__(256) void precompute_kernel(
    const float* __restrict__ guidance, const float* __restrict__ raw,
    half8* __restrict__ wgt, _Float16* __restrict__ bias,
    _Float16* __restrict__ state, int B, int H, int W)
{
    int idx = blockIdx.x * blockDim.x + threadIdx.x;
    int total = B * H * W;
    if (idx >= total) return;
    int x = idx % W;
    int y = (idx / W) % H;
    int b = idx / (W * H);

    const int dy[8] = {-1,-1,-1, 0, 0, 1, 1, 1};
    const int dx[8] = {-1, 0, 1,-1, 1,-1, 0, 1};

    float g[8];
    float s = 0.f;
#pragma unroll
    for (int c = 0; c < 8; ++c) {
        int yy = y + dy[c], xx = x + dx[c];
        float v = 0.f;
        if (yy >= 0 && yy < H && xx >= 0 && xx < W)
            v = guidance[(((size_t)b * 8 + c) * H + yy) * W + xx];
        g[c] = v;
        s += fabsf(v);
    }
    float inv = 1.f / fmaxf(s, EPSV);
    float wsum = 0.f;
#pragma unroll
    for (int c = 0; c < 8; ++c) { g[c] *= inv; wsum += g[c]; }

    half8 hw;
#pragma unroll
    for (int c = 0; c < 8; ++c) hw[c] = (_Float16)g[c];
    wgt[idx] = hw;

    float r = raw[idx];
    bias[idx]  = (_Float16)((1.f - wsum) * r);
    state[idx] = (_Float16)r;
}

// ---------------------------------------------------------------------------
// One tile: stage weights/bias/state into registers, FUSE Jacobi iterations
// (outside-tile = 0 each iter; px at distance >= k from tile edge exact after
// k iters -> 40x40 core exact at k=FUSE=12; out-of-image px have w=0,b=0,s=0
// -> stay 0 = zero-pad semantics), store core. Static store predicate.
// LDS hazard between consecutive tiles: iter k's write->sync->read orders
// tile-1's last reads before tile-2's first writes (same-parity buffers are
// separated by an intervening sync) -> no extra barrier needed.
// ---------------------------------------------------------------------------
template<bool LAST>
__device__ __forceinline__ void process_tile(
    int t, int qx, int seg,
    const _Float16* __restrict__ src, const half8* __restrict__ wgt,
    const _Float16* __restrict__ bias, _Float16* __restrict__ dst,
    float* __restrict__ dst32,
    float (*bufTop)[17][64], float (*bufBot)[17][64])
{
    const int H = 480, W = 640;
    int tx = t % TXN;
    int tmp = t / TXN;
    int ty = tmp % TYN;
    int b  = tmp / TYN;
    int x0 = tx * CORE - FUSE;
    int y0 = ty * CORE - FUSE;
    size_t plane = (size_t)b * H * W;

    int gx0 = x0 + qx * 4;                       // quad is fully in or out
    bool xok = (gx0 >= 0) & (gx0 + 3 < W);
    int gyb = y0 + seg * 4;

    half8 pw[4][4];
    float pb[4][4];
    float s[4][4];
#pragma unroll
    for (int r = 0; r < 4; ++r) {
        int gy = gyb + r;
        bool ok = xok && gy >= 0 && gy < H;
        if (ok) {
            size_t gb = plane + (size_t)gy * W + gx0;
            const half8* wp = wgt + gb;
            pw[r][0] = wp[0]; pw[r][1] = wp[1]; pw[r][2] = wp[2]; pw[r][3] = wp[3];
            half4 bq = *(const half4*)(bias + gb);
            half4 sq = *(const half4*)(src + gb);
#pragma unroll
            for (int c = 0; c < 4; ++c) {
                pb[r][c] = (float)bq[c];
                s[r][c]  = (float)sq[c];
            }
        } else {
            half8 hz;
#pragma unroll
            for (int c = 0; c < 8; ++c) hz[c] = (_Float16)0.f;
#pragma unroll
            for (int c = 0; c < 4; ++c) {
                pw[r][c] = hz; pb[r][c] = 0.f; s[r][c] = 0.f;
            }
        }
    }

#pragma unroll 2
    for (int it = 0; it < FUSE; ++it) {
        const int p = it & 1;
        *(float4*)&bufTop[p][seg][qx * 4]     = make_float4(s[0][0], s[0][1], s[0][2], s[0][3]);
        *(float4*)&bufBot[p][seg + 1][qx * 4] = make_float4(s[3][0], s[3][1], s[3][2], s[3][3]);
        __syncthreads();
        float4 Av = *(const float4*)&bufBot[p][seg][qx * 4];      // row above
        float4 Bv = *(const float4*)&bufTop[p][seg + 1][qx * 4];  // row below

        float u0 = Av.x, u1 = Av.y, u2 = Av.z, u3 = Av.w;
        float ul = dpp_from_left(u3);
        float ur = dpp_from_right(u0);
        float cl = dpp_from_left(s[0][3]);
        float cr = dpp_from_right(s[0][0]);
#pragma unroll
        for (int r = 0; r < 4; ++r) {
            float D0, D1, D2, D3;
            if (r < 3) { D0 = s[r+1][0]; D1 = s[r+1][1]; D2 = s[r+1][2]; D3 = s[r+1][3]; }
            else       { D0 = Bv.x;      D1 = Bv.y;      D2 = Bv.z;      D3 = Bv.w; }
            float dl = dpp_from_left(D3);
            float dr = dpp_from_right(D0);
            float C0 = s[r][0], C1 = s[r][1], C2 = s[r][2], C3 = s[r][3];
            half8 w0 = pw[r][0], w1 = pw[r][1], w2 = pw[r][2], w3 = pw[r][3];
            float n0 = pb[r][0]
                + (float)w0[0] * ul + (float)w0[1] * u0 + (float)w0[2] * u1
                + (float)w0[3] * cl + (float)w0[4] * C1
                + (float)w0[5] * dl + (float)w0[6] * D0 + (float)w0[7] * D1;
            float n1 = pb[r][1]
                + (float)w1[0] * u0 + (float)w1[1] * u1 + (float)w1[2] * u2
                + (float)w1[3] * C0 + (float)w1[4] * C2
                + (float)w1[5] * D0 + (float)w1[6] * D1 + (float)w1[7] * D2;
            float n2 = pb[r][2]
                + (float)w2[0] * u1 + (float)w2[1] * u2 + (float)w2[2] * u3
                + (float)w2[3] * C1 + (float)w2[4] * C3
                + (float)w2[5] * D1 + (float)w2[6] * D2 + (float)w2[7] * D3;
            float n3 = pb[r][3]
                + (float)w3[0] * u2 + (float)w3[1] * u3 + (float)w3[2] * ur
                + (float)w3[3] * C2 + (float)w3[4] * cr
                + (float)w3[5] * D2 + (float)w3[6] * D3 + (float)w3[7] * dr;
            u0 = C0; u1 = C1; u2 = C2; u3 = C3; ul = cl; ur = cr;
            cl = dl; cr = dr;
            s[r][0] = n0; s[r][1] = n1; s[r][2] = n2; s[r][3] = n3;
        }
    }

    // Store the 40x40 core: quads/strips 3..12 inclusive (static pattern);
    // all stored px unconditionally in-image (cores flush).
    bool core = (qx >= 3) & (qx < 13) & (seg >= 3) & (seg < 13);
    if (core) {
#pragma unroll
        for (int r = 0; r < 4; ++r) {
            int gy = gyb + r;
            size_t gb = plane + (size_t)gy * W + gx0;
            if (LAST) {
                *(float4*)(dst32 + gb) = make_float4(s[r][0], s[r][1], s[r][2], s[r][3]);
            } else {
                half4 hv;
                hv[0] = (_Float16)s[r][0]; hv[1] = (_Float16)s[r][1];
                hv[2] = (_Float16)s[r][2]; hv[3] = (_Float16)s[r][3];
                *(half4*)(dst + gb) = hv;
            }
        }
    }
}

// ---------------------------------------------------------------------------
// Kernel 2: each block processes tiles bid and bid+NBLK sequentially.
// ---------------------------------------------------------------------------
template<bool LAST>
__global__ __launch_bounds__(256) void prop_fused_kernel(
    const _Float16* __restrict__ src, const half8* __restrict__ wgt,
    const _Float16* __restrict__ bias, _Float16* __restrict__ dst,
    float* __restrict__ dst32)
{
    __shared__ __align__(16) float bufTop[2][17][64];
    __shared__ __align__(16) float bufBot[2][17][64];

    int tid = threadIdx.x;
    int qx  = tid & 15;
    int seg = tid >> 4;

    // Zero ring slots once (bufBot[*][0], bufTop[*][16] never rewritten).
    if (tid < 64) {
        bufBot[0][0][tid]  = 0.f; bufBot[1][0][tid]  = 0.f;
        bufTop[0][16][tid] = 0.f; bufTop[1][16][tid] = 0.f;
    }

    process_tile<LAST>(blockIdx.x, qx, seg, src, wgt, bias, dst, dst32,
                       bufTop, bufBot);
    process_tile<LAST>(blockIdx.x + NBLK, qx, seg, src, wgt, bias, dst, dst32,
                       bufTop, bufBot);
}

// ---------------------------------------------------------------------------
extern "C" void kernel_launch(void* const* d_in, const int* in_sizes, int n_in,
                              void* d_out, int out_size, void* d_ws, size_t ws_size,
                              hipStream_t stream) {
    const float* guidance = (const float*)d_in[0];
    const float* raw      = (const float*)d_in[1];
    float* out = (float*)d_out;

    const int B = 8, H = 480, W = 640;
    const size_t npix = (size_t)B * H * W;

    // Workspace: wgt half8 (npix*16B) | bias fp16 | p0 fp16 | p1 fp16
    half8*    wgt  = (half8*)d_ws;
    _Float16* bias = (_Float16*)((char*)d_ws + npix * sizeof(half8));
    _Float16* p0   = bias + npix;
    _Float16* p1   = p0 + npix;

    {
        int blocks = (int)((npix + 255) / 256);
        precompute_kernel<<<blocks, 256, 0, stream>>>(guidance, raw, wgt, bias,
                                                      p0, B, H, W);
    }

    // 2 launches x FUSE=12 = 24 iterations. p0 -> p1 -> out(f32).
    prop_fused_kernel<false><<<NBLK, 256, 0, stream>>>(p0, wgt, bias, p1, nullptr);
    prop_fused_kernel<true ><<<NBLK, 256, 0, stream>>>(p1, wgt, bias, nullptr, out);
}

// Round 15
// 94.583 us; speedup vs baseline: 4.2643x; 1.0988x over previous
//
#include <hip/hip_runtime.h>
#include <hip/hip_fp16.h>

// Affinity propagation: 24 Jacobi iterations of an 8-neighbor weighted stencil.
// OFFSETS (dy,dx): (-1,-1),(-1,0),(-1,1),(0,-1),(0,1),(1,-1),(1,0),(1,1)
// R15 = R12 (FUSE=12, 64x64 tile, 40x40 flush core, register weights, DPP
// horizontal + LDS vertical exchange, 1536 independent blocks x 2 launches)
// + XCD-aware tile swizzle: t = (bid%8)*192 + bid/8 -> XCD k processes batch
// image k (192 tiles, ~6MB wgt+bias+state) with row-major temporal locality,
// so halo weight re-reads (61MB/launch) hit the XCD's own L2.
// + half4-packed bias regs (R9 vs R10 A/B: neutral, -8 VGPR).
// LESSONS: __launch_bounds__(256,4) clamps VGPR->64 = spill (R8). 36px/thread
// = 256 VGPR spill (R13). Persistent 2-tile blocks serialize staging (R14).
// Runtime store bounds regress (R9/R10). Backfill > persistence.

#define EPSV 1e-6f
#define FUSE   12
#define CORE   40                 // output core per 64x64 tile
#define TXN    16                 // 640 / 40
#define TYN    12                 // 480 / 40
#define NBLK   (8 * TXN * TYN)    // 1536
#define TPI    (TXN * TYN)        // 192 tiles per image = NBLK/8

typedef __attribute__((ext_vector_type(8))) _Float16 half8;
typedef __attribute__((ext_vector_type(4))) _Float16 half4;

__device__ __forceinline__ float dpp_from_left(float v) {
    // lane i gets lane i-1's v (within 16-lane DPP row); qx==0 -> 0.
    int r = __builtin_amdgcn_update_dpp(0, __float_as_int(v), 0x111, 0xF, 0xF, true);
    return __int_as_float(r);
}
__device__ __forceinline__ float dpp_from_right(float v) {
    // lane i gets lane i+1's v; qx==15 -> 0.
    int r = __builtin_amdgcn_update_dpp(0, __float_as_int(v), 0x101, 0xF, 0xF, true);
    return __int_as_float(r);
}

// ---------------------------------------------------------------------------
// Kernel 1: normalize guidance -> fp16 weights (AoS), fp16 bias, fp16 state.
// ---------------------------------------------------------------------------
__global__ __launch_bounds__(256) void precompute_kernel(
    const float* __restrict__ guidance, const float* __restrict__ raw,
    half8* __restrict__ wgt, _Float16* __restrict__ bias,
    _Float16* __restrict__ state, int B, int H, int W)
{
    int idx = blockIdx.x * blockDim.x + threadIdx.x;
    int total = B * H * W;
    if (idx >= total) return;
    int x = idx % W;
    int y = (idx / W) % H;
    int b = idx / (W * H);

    const int dy[8] = {-1,-1,-1, 0, 0, 1, 1, 1};
    const int dx[8] = {-1, 0, 1,-1, 1,-1, 0, 1};

    float g[8];
    float s = 0.f;
#pragma unroll
    for (int c = 0; c < 8; ++c) {
        int yy = y + dy[c], xx = x + dx[c];
        float v = 0.f;
        if (yy >= 0 && yy < H && xx >= 0 && xx < W)
            v = guidance[(((size_t)b * 8 + c) * H + yy) * W + xx];
        g[c] = v;
        s += fabsf(v);
    }
    float inv = 1.f / fmaxf(s, EPSV);
    float wsum = 0.f;
#pragma unroll
    for (int c = 0; c < 8; ++c) { g[c] *= inv; wsum += g[c]; }

    half8 hw;
#pragma unroll
    for (int c = 0; c < 8; ++c) hw[c] = (_Float16)g[c];
    wgt[idx] = hw;

    float r = raw[idx];
    bias[idx]  = (_Float16)((1.f - wsum) * r);
    state[idx] = (_Float16)r;
}

// ---------------------------------------------------------------------------
// Kernel 2: FUSE Jacobi iterations with state in registers.
// Tile = 64x64 px at origin (40*tx-12, 40*ty-12); outside-tile treated as 0
// each iteration (recompute ring): after k iters px at distance >= k from the
// tile edge are exact, so the 40x40 core (distance 12) is exact at k=FUSE=12.
// Out-of-image px have w=0,b=0,s=0 -> stay 0, matching zero-pad semantics.
// Cores tile the image disjointly and exactly (16x12 grid of 40x40).
// XCD swizzle: t = (bid%8)*TPI + bid/8 -> XCD k gets image k contiguously.
// ---------------------------------------------------------------------------
template<bool LAST>
__global__ __launch_bounds__(256) void prop_fused_kernel(
    const _Float16* __restrict__ src, const half8* __restrict__ wgt,
    const _Float16* __restrict__ bias, _Float16* __restrict__ dst,
    float* __restrict__ dst32)
{
    const int H = 480, W = 640;
    // bufTop[p][s][x]: strip s's row0 (read as "below-row" by strip s-1 at
    // index s; slot 16 stays 0). bufBot[p][s+1][x]: strip s's row3 (read as
    // "above-row" by strip s+1 at index s+1; slot 0 stays 0).
    __shared__ __align__(16) float bufTop[2][17][64];
    __shared__ __align__(16) float bufBot[2][17][64];

    int tid = threadIdx.x;
    int qx = tid & 15;          // x-quad within tile (DPP row position)
    int sy = tid >> 4;          // 4-row strip within tile

    // XCD-aware swizzle (bijective; NBLK % 8 == 0): round-robin XCD
    // assignment (bid%8) -> XCD k processes tiles [k*TPI, (k+1)*TPI) =
    // exactly batch image k, row-major -> halo re-reads stay in its L2.
    int t = (blockIdx.x & 7) * TPI + (blockIdx.x >> 3);
    int tx = t % TXN;
    int tmp = t / TXN;
    int ty = tmp % TYN;
    int b  = tmp / TYN;
    int x0 = tx * CORE - FUSE;
    int y0 = ty * CORE - FUSE;
    size_t plane = (size_t)b * H * W;

    int gx0 = x0 + qx * 4;                       // quad is fully in or out
    bool xok = (gx0 >= 0) & (gx0 + 3 < W);
    int gyb = y0 + sy * 4;

    if (tid < 64) {
        bufBot[0][0][tid]  = 0.f; bufBot[1][0][tid]  = 0.f;
        bufTop[0][16][tid] = 0.f; bufTop[1][16][tid] = 0.f;
    }

    // Per-px weights (half8 = 4 VGPR), bias packed fp16 (A/B-neutral), f32 state.
    half8 pw[4][4];
    half4 pbq[4];
    float s[4][4];
#pragma unroll
    for (int r = 0; r < 4; ++r) {
        int gy = gyb + r;
        bool ok = xok && gy >= 0 && gy < H;
        if (ok) {
            size_t gb = plane + (size_t)gy * W + gx0;
            const half8* wp = wgt + gb;
            pw[r][0] = wp[0]; pw[r][1] = wp[1]; pw[r][2] = wp[2]; pw[r][3] = wp[3];
            pbq[r] = *(const half4*)(bias + gb);
            half4 sq = *(const half4*)(src + gb);
#pragma unroll
            for (int c = 0; c < 4; ++c) s[r][c] = (float)sq[c];
        } else {
            half8 hz;
#pragma unroll
            for (int c = 0; c < 8; ++c) hz[c] = (_Float16)0.f;
            half4 z4;
#pragma unroll
            for (int c = 0; c < 4; ++c) z4[c] = (_Float16)0.f;
            pbq[r] = z4;
#pragma unroll
            for (int c = 0; c < 4; ++c) { pw[r][c] = hz; s[r][c] = 0.f; }
        }
    }

#pragma unroll 2
    for (int it = 0; it < FUSE; ++it) {
        const int p = it & 1;
        // Exchange strip-boundary rows (old values).
        *(float4*)&bufTop[p][sy][qx * 4]     = make_float4(s[0][0], s[0][1], s[0][2], s[0][3]);
        *(float4*)&bufBot[p][sy + 1][qx * 4] = make_float4(s[3][0], s[3][1], s[3][2], s[3][3]);
        __syncthreads();
        float4 Av = *(const float4*)&bufBot[p][sy][qx * 4];      // row above strip
        float4 Bv = *(const float4*)&bufTop[p][sy + 1][qx * 4];  // row below strip

        // Rolling in-place update (wave-uniform, so DPP of carry regs is safe).
        float u0 = Av.x, u1 = Av.y, u2 = Av.z, u3 = Av.w;
        float ul = dpp_from_left(u3);
        float ur = dpp_from_right(u0);
        float cl = dpp_from_left(s[0][3]);
        float cr = dpp_from_right(s[0][0]);
#pragma unroll
        for (int r = 0; r < 4; ++r) {
            float D0, D1, D2, D3;
            if (r < 3) { D0 = s[r+1][0]; D1 = s[r+1][1]; D2 = s[r+1][2]; D3 = s[r+1][3]; }
            else       { D0 = Bv.x;      D1 = Bv.y;      D2 = Bv.z;      D3 = Bv.w; }
            float dl = dpp_from_left(D3);
            float dr = dpp_from_right(D0);
            float C0 = s[r][0], C1 = s[r][1], C2 = s[r][2], C3 = s[r][3];
            half8 w0 = pw[r][0], w1 = pw[r][1], w2 = pw[r][2], w3 = pw[r][3];
            float n0 = (float)pbq[r][0]
                + (float)w0[0] * ul + (float)w0[1] * u0 + (float)w0[2] * u1
                + (float)w0[3] * cl + (float)w0[4] * C1
                + (float)w0[5] * dl + (float)w0[6] * D0 + (float)w0[7] * D1;
            float n1 = (float)pbq[r][1]
                + (float)w1[0] * u0 + (float)w1[1] * u1 + (float)w1[2] * u2
                + (float)w1[3] * C0 + (float)w1[4] * C2
                + (float)w1[5] * D0 + (float)w1[6] * D1 + (float)w1[7] * D2;
            float n2 = (float)pbq[r][2]
                + (float)w2[0] * u1 + (float)w2[1] * u2 + (float)w2[2] * u3
                + (float)w2[3] * C1 + (float)w2[4] * C3
                + (float)w2[5] * D1 + (float)w2[6] * D2 + (float)w2[7] * D3;
            float n3 = (float)pbq[r][3]
                + (float)w3[0] * u2 + (float)w3[1] * u3 + (float)w3[2] * ur
                + (float)w3[3] * C2 + (float)w3[4] * cr
                + (float)w3[5] * D2 + (float)w3[6] * D3 + (float)w3[7] * dr;
            u0 = C0; u1 = C1; u2 = C2; u3 = C3; ul = cl; ur = cr;
            cl = dl; cr = dr;
            s[r][0] = n0; s[r][1] = n1; s[r][2] = n2; s[r][3] = n3;
        }
    }

    // Store the 40x40 core: quads/strips 3..12 inclusive. Static lane-pattern
    // predicate; all stored px are unconditionally in-image (cores flush).
    bool core = (qx >= 3) & (qx < 13) & (sy >= 3) & (sy < 13);
    if (core) {
#pragma unroll
        for (int r = 0; r < 4; ++r) {
            int gy = gyb + r;                       // in [0,480) by construction
            size_t gb = plane + (size_t)gy * W + gx0;
            if (LAST) {
                *(float4*)(dst32 + gb) = make_float4(s[r][0], s[r][1], s[r][2], s[r][3]);
            } else {
                half4 hv;
                hv[0] = (_Float16)s[r][0]; hv[1] = (_Float16)s[r][1];
                hv[2] = (_Float16)s[r][2]; hv[3] = (_Float16)s[r][3];
                *(half4*)(dst + gb) = hv;
            }
        }
    }
}

// ---------------------------------------------------------------------------
extern "C" void kernel_launch(void* const* d_in, const int* in_sizes, int n_in,
                              void* d_out, int out_size, void* d_ws, size_t ws_size,
                              hipStream_t stream) {
    const float* guidance = (const float*)d_in[0];
    const float* raw      = (const float*)d_in[1];
    float* out = (float*)d_out;

    const int B = 8, H = 480, W = 640;
    const size_t npix = (size_t)B * H * W;

    // Workspace: wgt half8 (npix*16B) | bias fp16 | p0 fp16 | p1 fp16
    half8*    wgt  = (half8*)d_ws;
    _Float16* bias = (_Float16*)((char*)d_ws + npix * sizeof(half8));
    _Float16* p0   = bias + npix;
    _Float16* p1   = p0 + npix;

    {
        int blocks = (int)((npix + 255) / 256);
        precompute_kernel<<<blocks, 256, 0, stream>>>(guidance, raw, wgt, bias,
                                                      p0, B, H, W);
    }

    // 2 launches x FUSE=12 = 24 iterations. p0 -> p1 -> out(f32).
    prop_fused_kernel<false><<<NBLK, 256, 0, stream>>>(p0, wgt, bias, p1, nullptr);
    prop_fused_kernel<true ><<<NBLK, 256, 0, stream>>>(p1, wgt, bias, nullptr, out);
}